// Round 1
// 2257.663 us; speedup vs baseline: 2.4136x; 2.4136x over previous
//
#include <hip/hip_runtime.h>

// Problem constants (reference: B=2, T=2048, C=1024, V=8192, L=2, H=16, d=64)
#define BB 2
#define TT 2048
#define CC 1024
#define VV 8192
#define LL 2
#define HH 16
#define DD 64
#define MM (BB * TT) // 4096 rows

// R5: flash attention moved to MFMA (v_mfma_f32_16x16x32_bf16).
// Old VALU flash: 2 x 1733 us, MfmaUtil=0, VGPR=256, occupancy 12% -> 64% of
// total runtime on the vector ALU. New structure: block = 4 waves / 64 queries,
// wave w owns rows [qb+16w, qb+16w+16); KV tiles of 32 keys staged in LDS
// (K row-major + XOR swizzle slot^=(key&7); V transposed [d][key] with
// key^=((d>>3)&3)<<3 swizzle) -> all MFMA fragment reads are conflict-free
// ds_read_b128. Online softmax in C-layout regs via __shfl_xor(1/2/4/8)
// within 16-lane column groups. P goes through a 1KB/wave LDS buffer to form
// the PV A-fragment. Register double-buffered staging hides HBM latency.
using u16 = unsigned short;

typedef short bf16x8 __attribute__((ext_vector_type(8)));   // 8 bf16 = 4 VGPRs
typedef float f32x4 __attribute__((ext_vector_type(4)));    // MFMA accumulator

__device__ __forceinline__ float bf2f(u16 u) {
    union { unsigned int i; float f; } x;
    x.i = ((unsigned int)u) << 16;
    return x.f;
}
__device__ __forceinline__ u16 f2bf(float f) {
    union { float f; unsigned int i; } x;
    x.f = f;
    unsigned int r = x.i + 0x7fffu + ((x.i >> 16) & 1u); // round-to-nearest-even
    return (u16)(r >> 16);
}

// ---------- 0. dtype probe (kept from R4 — resolves fp32-vs-bf16 at runtime) ----------
__global__ __launch_bounds__(256) void probe_kernel(const u16* __restrict__ w,
                                                    int* __restrict__ flag) {
    __shared__ int cnt;
    if (threadIdx.x == 0) cnt = 0;
    __syncthreads();
    int c = 0;
    for (int i = threadIdx.x; i < 4096; i += 256) {
        const u16 u = w[2 * i];
        const int e = (u >> 7) & 0xff;
        if (e >= 125) ++c;
    }
    atomicAdd(&cnt, c);
    __syncthreads();
    if (threadIdx.x == 0) *flag = (cnt > 64) ? 1 : 0;
}

// ---------- 1. embedding + positional -> bf16 h ----------
__global__ __launch_bounds__(256) void embed_kernel(const int* __restrict__ x,
                                                    const void* __restrict__ ew,
                                                    const void* __restrict__ pos,
                                                    u16* __restrict__ h,
                                                    const int* __restrict__ flagp) {
    const int f = *flagp;
    const int i = blockIdx.x;        // token row 0..MM-1
    const int t = i & (TT - 1);      // position within sequence
    const int row = x[i];
    const int c = threadIdx.x * 4;
    float4 e, p;
    if (f) {
        e = *(const float4*)((const float*)ew + (size_t)row * CC + c);
        p = *(const float4*)((const float*)pos + (size_t)t * CC + c);
    } else {
        ushort4 eu = *(const ushort4*)((const u16*)ew + (size_t)row * CC + c);
        ushort4 pu = *(const ushort4*)((const u16*)pos + (size_t)t * CC + c);
        e = make_float4(bf2f(eu.x), bf2f(eu.y), bf2f(eu.z), bf2f(eu.w));
        p = make_float4(bf2f(pu.x), bf2f(pu.y), bf2f(pu.z), bf2f(pu.w));
    }
    ushort4 o;
    o.x = f2bf(e.x + p.x); o.y = f2bf(e.y + p.y);
    o.z = f2bf(e.z + p.z); o.w = f2bf(e.w + p.w);
    *(ushort4*)&h[(size_t)i * CC + c] = o;
}

// ---------- 2. GEMM: out[m,n] = sum_k A[m,k]*W[n,k] (+bias[n]) (+res[m,n]) ----------
// A bf16 [M,K] (ours). W/bias: dtype per flag, element offsets passed in.
// 128x128 tile, BK=16, 256 threads, 8x8 micro-tile, fp32 FMA.
__global__ __launch_bounds__(256) void gemm_nt(const u16* __restrict__ A,
                                               const void* __restrict__ W, size_t wOff,
                                               void* __restrict__ outP,
                                               const void* __restrict__ bias, size_t bOff,
                                               const u16* __restrict__ res,
                                               int M, int N, int K, int outFlagged,
                                               const int* __restrict__ flagp) {
    const int f = *flagp;
    __shared__ float As[16][128];
    __shared__ float Bs[16][128];
    const int tid = threadIdx.x;
    const int tx = tid & 15;   // 16 col-groups of 8
    const int ty = tid >> 4;   // 16 row-groups of 8
    const int m0 = blockIdx.y * 128, n0 = blockIdx.x * 128;

    const int ar = tid >> 1;          // 0..127 (row within tile)
    const int ak = (tid & 1) * 8;     // k offset 0,8

    float acc[8][8] = {};

    for (int kt = 0; kt < K; kt += 16) {
        uint4 a4 = *(const uint4*)&A[(size_t)(m0 + ar) * K + kt + ak];
        float wv[8];
        if (f) {
            const float* Wf = (const float*)W + wOff;
            *(float4*)&wv[0] = *(const float4*)&Wf[(size_t)(n0 + ar) * K + kt + ak];
            *(float4*)&wv[4] = *(const float4*)&Wf[(size_t)(n0 + ar) * K + kt + ak + 4];
        } else {
            const u16* Wb = (const u16*)W + wOff;
            uint4 w4 = *(const uint4*)&Wb[(size_t)(n0 + ar) * K + kt + ak];
            wv[0] = bf2f((u16)(w4.x & 0xffffu)); wv[1] = bf2f((u16)(w4.x >> 16));
            wv[2] = bf2f((u16)(w4.y & 0xffffu)); wv[3] = bf2f((u16)(w4.y >> 16));
            wv[4] = bf2f((u16)(w4.z & 0xffffu)); wv[5] = bf2f((u16)(w4.z >> 16));
            wv[6] = bf2f((u16)(w4.w & 0xffffu)); wv[7] = bf2f((u16)(w4.w >> 16));
        }
        As[ak + 0][ar] = bf2f((u16)(a4.x & 0xffffu));
        As[ak + 1][ar] = bf2f((u16)(a4.x >> 16));
        As[ak + 2][ar] = bf2f((u16)(a4.y & 0xffffu));
        As[ak + 3][ar] = bf2f((u16)(a4.y >> 16));
        As[ak + 4][ar] = bf2f((u16)(a4.z & 0xffffu));
        As[ak + 5][ar] = bf2f((u16)(a4.z >> 16));
        As[ak + 6][ar] = bf2f((u16)(a4.w & 0xffffu));
        As[ak + 7][ar] = bf2f((u16)(a4.w >> 16));
        Bs[ak + 0][ar] = wv[0]; Bs[ak + 1][ar] = wv[1];
        Bs[ak + 2][ar] = wv[2]; Bs[ak + 3][ar] = wv[3];
        Bs[ak + 4][ar] = wv[4]; Bs[ak + 5][ar] = wv[5];
        Bs[ak + 6][ar] = wv[6]; Bs[ak + 7][ar] = wv[7];
        __syncthreads();
#pragma unroll
        for (int kk = 0; kk < 16; ++kk) {
            float av[8], bv[8];
            *(float4*)&av[0] = *(const float4*)&As[kk][ty * 8];
            *(float4*)&av[4] = *(const float4*)&As[kk][ty * 8 + 4];
            *(float4*)&bv[0] = *(const float4*)&Bs[kk][tx * 8];
            *(float4*)&bv[4] = *(const float4*)&Bs[kk][tx * 8 + 4];
#pragma unroll
            for (int i = 0; i < 8; ++i)
#pragma unroll
                for (int j = 0; j < 8; ++j)
                    acc[i][j] += av[i] * bv[j];
        }
        __syncthreads();
    }

#pragma unroll
    for (int i = 0; i < 8; ++i) {
        const int m = m0 + ty * 8 + i;
#pragma unroll
        for (int j = 0; j < 8; j += 4) {
            const int n = n0 + tx * 8 + j;
            float4 vv = make_float4(acc[i][j], acc[i][j + 1], acc[i][j + 2], acc[i][j + 3]);
            if (bias) {
                if (f) {
                    float4 bb = *(const float4*)((const float*)bias + bOff + n);
                    vv.x += bb.x; vv.y += bb.y; vv.z += bb.z; vv.w += bb.w;
                } else {
                    ushort4 bb = *(const ushort4*)((const u16*)bias + bOff + n);
                    vv.x += bf2f(bb.x); vv.y += bf2f(bb.y);
                    vv.z += bf2f(bb.z); vv.w += bf2f(bb.w);
                }
            }
            if (res) {
                ushort4 rr = *(const ushort4*)&res[(size_t)m * N + n];
                vv.x += bf2f(rr.x); vv.y += bf2f(rr.y);
                vv.z += bf2f(rr.z); vv.w += bf2f(rr.w);
            }
            if (outFlagged && f) {
                *(float4*)((float*)outP + (size_t)m * N + n) = vv;
            } else {
                ushort4 ob;
                ob.x = f2bf(vv.x); ob.y = f2bf(vv.y);
                ob.z = f2bf(vv.z); ob.w = f2bf(vv.w);
                *(ushort4*)((u16*)outP + (size_t)m * N + n) = ob;
            }
        }
    }
}

// ---------- 3. MFMA flash attention ----------
// grid = (B*H, T/64), blockIdx.y reversed (heavy q-tiles first). 256 threads =
// 4 waves; wave w owns q rows [qb+16w, qb+16w+16). KV tiles of 32 keys.
// Per tile per wave: 4 MFMA (QK^T, K=64 contraction in 2 chunks) + online
// softmax + 4 MFMA (PV). MFMA layouts (m89/m97-verified):
//   A: row=lane&15, k=(lane>>4)*8+j      B: col=lane&15, k=(lane>>4)*8+j
//   C: col=lane&15, row=(lane>>4)*4+reg
// LDS: Ks [32 key][8 slot16B], slot stores d-octet (slot^(key&7))  -> QK B-frag
//      Vt [64 d][32 key] bf16, key stored at key^(((d>>3)&3)<<3)   -> PV B-frag
//      Pw [4][16 q][32 key] bf16 per-wave                          -> PV A-frag
// All three fragment reads are conflict-free ds_read_b128 (8 lanes per 16B
// bank-group slot).
__global__ __launch_bounds__(256) void flash_attn(const u16* __restrict__ q,
                                                  const u16* __restrict__ k,
                                                  const u16* __restrict__ v,
                                                  u16* __restrict__ ctx) {
    const int bh = blockIdx.x;          // 0..B*H-1
    const int b = bh >> 4;              // /HH
    const int hd = bh & 15;             // %HH
    const int qt = gridDim.y - 1 - blockIdx.y;  // heavy tiles first
    const int qb = qt * 64;
    const int tid = threadIdx.x;
    const int w = tid >> 6;             // wave 0..3
    const int lane = tid & 63;
    const int l15 = lane & 15;
    const int l4 = lane >> 4;           // 0..3
    const int qw = qb + w * 16;         // wave's first query row
    const float scale = 0.125f;         // 1/sqrt(64)

    __shared__ u16 KsS[32 * 64];        // 4KB
    __shared__ u16 VtS[64 * 32];        // 4KB (transposed V)
    __shared__ u16 PwS[4][16 * 32];     // 4KB (per-wave P)
    char* Ks = (char*)KsS;
    char* Vt = (char*)VtS;
    char* Pw = (char*)PwS[w];

    // Q fragments (A operand), held in registers for the whole block
    const size_t qoff = ((size_t)(b * TT + qw + l15)) * CC + hd * DD + l4 * 8;
    const bf16x8 qf0 = *(const bf16x8*)(q + qoff);        // d 0..31 chunk
    const bf16x8 qf1 = *(const bf16x8*)(q + qoff + 32);   // d 32..63 chunk

    f32x4 zero4 = {0.f, 0.f, 0.f, 0.f};
    f32x4 ctxa[4] = {zero4, zero4, zero4, zero4};         // ctx[16 q][64 d]
    float m[4]    = {-1e30f, -1e30f, -1e30f, -1e30f};     // running row max
    float lsum[4] = {0.f, 0.f, 0.f, 0.f};                 // per-lane partial denom

    // block-cooperative staging assignment: thread -> (key row, d-octet)
    const int skey = tid >> 3;          // 0..31
    const int sd8 = tid & 7;            // 0..7
    const int kWByte = skey * 128 + ((sd8 ^ (skey & 7)) << 4);      // swizzled K dest
    const int keyx2 = (skey ^ ((sd8 & 3) << 3)) * 2;                // swizzled Vt key

    const int nt = qt * 2 + 2;          // 32-key tiles covering [0, qb+64)

    uint4 kreg, vreg;                   // register double-buffer for staging
    {
        const size_t g = ((size_t)(b * TT + skey)) * CC + hd * DD + sd8 * 8;
        kreg = *(const uint4*)(k + g);
        vreg = *(const uint4*)(v + g);
    }

    for (int t = 0; t < nt; ++t) {
        const int kv0 = t * 32;
        // ---- write staged regs -> LDS ----
        *(uint4*)(Ks + kWByte) = kreg;
        {
            const u16* vr = (const u16*)&vreg;
#pragma unroll
            for (int j = 0; j < 8; ++j)     // Vt[d][key'] transpose-scatter
                *(u16*)(Vt + (sd8 * 8 + j) * 64 + keyx2) = vr[j];
        }
        __syncthreads();
        // ---- issue next tile's global loads (latency hides under compute) ----
        if (t + 1 < nt) {
            const size_t g = ((size_t)(b * TT + kv0 + 32 + skey)) * CC + hd * DD + sd8 * 8;
            kreg = *(const uint4*)(k + g);
            vreg = *(const uint4*)(v + g);
        }
        if (kv0 <= qw + 15) {   // wave-uniform: skip fully-masked tiles
            // ---- QK^T: S[16 q][32 key], 2 C-tiles x 2 K-chunks ----
            f32x4 s[2];
#pragma unroll
            for (int c = 0; c < 2; ++c) {
                const int key = c * 16 + l15;
                const int kb = key * 128;
                const int kx = key & 7;
                const bf16x8 kf0 = *(const bf16x8*)(Ks + kb + ((l4 ^ kx) << 4));
                const bf16x8 kf1 = *(const bf16x8*)(Ks + kb + (((4 + l4) ^ kx) << 4));
                f32x4 z = {0.f, 0.f, 0.f, 0.f};
                z = __builtin_amdgcn_mfma_f32_16x16x32_bf16(qf0, kf0, z, 0, 0, 0);
                z = __builtin_amdgcn_mfma_f32_16x16x32_bf16(qf1, kf1, z, 0, 0, 0);
                s[c] = z;
            }
            // ---- scale + causal mask (element: key <= row) ----
            float sv[2][4];
#pragma unroll
            for (int c = 0; c < 2; ++c) {
                const int key = kv0 + c * 16 + l15;
#pragma unroll
                for (int r = 0; r < 4; ++r) {
                    const int row = qw + l4 * 4 + r;
                    sv[c][r] = (key <= row) ? s[c][r] * scale : -1e30f;
                }
            }
            // ---- online softmax (row spread over 16 lanes; xor 1/2/4/8 stays in group) ----
#pragma unroll
            for (int r = 0; r < 4; ++r) {
                float mt = fmaxf(sv[0][r], sv[1][r]);
                mt = fmaxf(mt, __shfl_xor(mt, 1, 64));
                mt = fmaxf(mt, __shfl_xor(mt, 2, 64));
                mt = fmaxf(mt, __shfl_xor(mt, 4, 64));
                mt = fmaxf(mt, __shfl_xor(mt, 8, 64));
                const float mn = fmaxf(m[r], mt);
                const float corr = __expf(m[r] - mn);   // 0 on first tile (m=-1e30)
                m[r] = mn;
                const float p0 = __expf(sv[0][r] - mn); // masked -> exp(-1e30)=0
                const float p1 = __expf(sv[1][r] - mn);
                lsum[r] = lsum[r] * corr + p0 + p1;
#pragma unroll
                for (int nb = 0; nb < 4; ++nb) ctxa[nb][r] *= corr;
                const int rowb = (l4 * 4 + r) * 64;
                *(u16*)(Pw + rowb + l15 * 2) = f2bf(p0);
                *(u16*)(Pw + rowb + 32 + l15 * 2) = f2bf(p1);
            }
            // ---- PV: ctx += P[16x32] * V[32x64] ----
            const bf16x8 pf = *(const bf16x8*)(Pw + l15 * 64 + l4 * 16);  // A-frag
#pragma unroll
            for (int nb = 0; nb < 4; ++nb) {
                const int d = nb * 16 + l15;
                const bf16x8 vf = *(const bf16x8*)(Vt + d * 64 + ((l4 ^ ((d >> 3) & 3)) << 4));
                ctxa[nb] = __builtin_amdgcn_mfma_f32_16x16x32_bf16(pf, vf, ctxa[nb], 0, 0, 0);
            }
        }
        __syncthreads();
    }

    // ---- epilogue: reduce denominators across the 16 column lanes, write bf16 ----
    float inv[4];
#pragma unroll
    for (int r = 0; r < 4; ++r) {
        float sred = lsum[r];
        sred += __shfl_xor(sred, 1, 64);
        sred += __shfl_xor(sred, 2, 64);
        sred += __shfl_xor(sred, 4, 64);
        sred += __shfl_xor(sred, 8, 64);
        inv[r] = 1.0f / sred;   // >0: key 0 is always unmasked in tile 0
    }
    u16* cp = ctx + ((size_t)(b * TT + qw)) * CC + hd * DD;
#pragma unroll
    for (int r = 0; r < 4; ++r) {
        const size_t rb = (size_t)(l4 * 4 + r) * CC;
#pragma unroll
        for (int nb = 0; nb < 4; ++nb)
            cp[rb + nb * 16 + l15] = f2bf(ctxa[nb][r] * inv[r]);
    }
}

// ---------- 4. d2d copy (h -> scratch), 16B per thread ----------
__global__ __launch_bounds__(256) void copy16_kernel(const uint4* __restrict__ src,
                                                     uint4* __restrict__ dst) {
    const size_t i = (size_t)blockIdx.x * 256 + threadIdx.x;
    dst[i] = src[i];
}

// ---------- 5. loss: per-row logsumexp + NLL ----------
__global__ __launch_bounds__(256) void loss_row(const void* __restrict__ logits,
                                                const int* __restrict__ target,
                                                float* __restrict__ nll,
                                                const int* __restrict__ flagp) {
    const int f = *flagp;
    const int r = blockIdx.x;
    __shared__ float red[4];
    const float* lpf = (const float*)logits + (size_t)r * VV;
    const u16*   lpb = (const u16*)logits + (size_t)r * VV;

    float lmax = -1e30f;
    if (f) { for (int i = threadIdx.x; i < VV; i += 256) lmax = fmaxf(lmax, lpf[i]); }
    else   { for (int i = threadIdx.x; i < VV; i += 256) lmax = fmaxf(lmax, bf2f(lpb[i])); }
#pragma unroll
    for (int off = 32; off > 0; off >>= 1) lmax = fmaxf(lmax, __shfl_down(lmax, off, 64));
    const int wid = threadIdx.x >> 6, lid = threadIdx.x & 63;
    if (lid == 0) red[wid] = lmax;
    __syncthreads();
    lmax = fmaxf(fmaxf(red[0], red[1]), fmaxf(red[2], red[3]));

    float sum = 0.f;
    if (f) { for (int i = threadIdx.x; i < VV; i += 256) sum += __expf(lpf[i] - lmax); }
    else   { for (int i = threadIdx.x; i < VV; i += 256) sum += __expf(bf2f(lpb[i]) - lmax); }
#pragma unroll
    for (int off = 32; off > 0; off >>= 1) sum += __shfl_down(sum, off, 64);
    __syncthreads();
    if (lid == 0) red[wid] = sum;
    __syncthreads();
    if (threadIdx.x == 0) {
        const float s = red[0] + red[1] + red[2] + red[3];
        const float tl = f ? lpf[target[r]] : bf2f(lpb[target[r]]);
        nll[r] = lmax + __logf(s) - tl;   // = -(log_softmax at target)
    }
}

__global__ __launch_bounds__(256) void loss_final(const float* __restrict__ nll,
                                                  void* __restrict__ out,
                                                  const int* __restrict__ flagp) {
    __shared__ float red[4];
    float s = 0.f;
    for (int i = threadIdx.x; i < MM; i += 256) s += nll[i];
#pragma unroll
    for (int off = 32; off > 0; off >>= 1) s += __shfl_down(s, off, 64);
    if ((threadIdx.x & 63) == 0) red[threadIdx.x >> 6] = s;
    __syncthreads();
    if (threadIdx.x == 0) {
        const float t = (red[0] + red[1] + red[2] + red[3]) / (float)MM;
        if (*flagp) ((float*)out)[(size_t)MM * VV] = t;
        else        ((u16*)out)[(size_t)MM * VV] = f2bf(t);
    }
}

// ---------- launch ----------
extern "C" void kernel_launch(void* const* d_in, const int* in_sizes, int n_in,
                              void* d_out, int out_size, void* d_ws, size_t ws_size,
                              hipStream_t stream) {
    const int* x      = (const int*)d_in[0];
    const int* target = (const int*)d_in[1];
    const void* ew  = d_in[2];
    const void* pos = d_in[3];
    const void* Wq  = d_in[4];
    const void* bq  = d_in[5];
    const void* Wk  = d_in[6];
    const void* bk  = d_in[7];
    const void* Wv  = d_in[8];
    const void* bv  = d_in[9];
    const void* Wo  = d_in[10];
    const void* bo  = d_in[11];
    const void* Wu  = d_in[12];

    int* flagp = (int*)d_ws;   // 4 bytes of workspace: dtype flag

    // bf16 scratch inside d_out (dead until logits GEMM; >=64 MiB both modes):
    u16* outw = (u16*)d_out;
    u16* hB  = outw;
    u16* qB  = outw + (size_t)1 * MM * CC;
    u16* kB  = outw + (size_t)2 * MM * CC;
    u16* vB  = outw + (size_t)3 * MM * CC;
    u16* ctx = qB;  // flash block writes exactly the (row, head-slice) it read
    // Scratch inside the consumed embed_w buffer (>=16 MiB both modes):
    u16* hScr  = (u16*)ew;                                   // [0, 8M) bytes
    float* nll = (float*)((char*)ew + 12u * 1024 * 1024);    // [12M, 12M+16K)

    probe_kernel<<<1, 256, 0, stream>>>((const u16*)Wu, flagp);
    embed_kernel<<<MM, 256, 0, stream>>>(x, ew, pos, hB, flagp);  // last read of ew

    const dim3 gP(CC / 128, MM / 128);   // projection GEMMs: 8 x 32 blocks
    for (int l = 0; l < LL; ++l) {
        const size_t wOff = (size_t)l * CC * CC, bOff = (size_t)l * CC;
        gemm_nt<<<gP, 256, 0, stream>>>(hB, Wq, wOff, qB, bq, bOff, nullptr, MM, CC, CC, 0, flagp);
        gemm_nt<<<gP, 256, 0, stream>>>(hB, Wk, wOff, kB, bk, bOff, nullptr, MM, CC, CC, 0, flagp);
        gemm_nt<<<gP, 256, 0, stream>>>(hB, Wv, wOff, vB, bv, bOff, nullptr, MM, CC, CC, 0, flagp);
        flash_attn<<<dim3(BB * HH, TT / 64), 256, 0, stream>>>(qB, kB, vB, ctx);
        // out-proj + residual, in-place into hB (res read/write at identical (m,n))
        gemm_nt<<<gP, 256, 0, stream>>>(ctx, Wo, wOff, hB, bo, bOff, hB, MM, CC, CC, 0, flagp);
    }

    // move h out of d_out, then logits GEMM overwrites d_out (dtype per flag)
    copy16_kernel<<<(MM * CC * 2 / 16) / 256, 256, 0, stream>>>((const uint4*)hB, (uint4*)hScr);
    gemm_nt<<<dim3(VV / 128, MM / 128), 256, 0, stream>>>(hScr, Wu, 0, d_out,
                                                          nullptr, 0, nullptr, MM, VV, CC, 1, flagp);
    loss_row<<<MM, 256, 0, stream>>>(d_out, target, nll, flagp);
    loss_final<<<1, 256, 0, stream>>>(nll, d_out, flagp);
}

// Round 2
// 1166.561 us; speedup vs baseline: 4.6710x; 1.9353x over previous
//
#include <hip/hip_runtime.h>

// Problem constants (reference: B=2, T=2048, C=1024, V=8192, L=2, H=16, d=64)
#define BB 2
#define TT 2048
#define CC 1024
#define VV 8192
#define LL 2
#define HH 16
#define DD 64
#define MM (BB * TT) // 4096 rows

// R6: GEMMs moved to MFMA. R5 counters: logits gemm 830us @ MfmaUtil=0,
// VALUBusy=67%, 8.4e7 LDS bank conflicts; projections same structure.
// New: cvt_w pre-pass (weights -> bf16 scratch once), gemm_bf16 128x128 tile
// BK=64, 4 waves x (64x64), XOR-swizzled LDS (slot = octet ^ (row&7) on 128B
// rows -> balanced banks for ds_read_b128/ds_write_b128), reg-staged with
// next-tile loads issued under the MFMA phase (T14 ordering).
using u16 = unsigned short;

typedef short bf16x8 __attribute__((ext_vector_type(8)));   // 8 bf16 = 4 VGPRs
typedef float f32x4 __attribute__((ext_vector_type(4)));    // MFMA accumulator

__device__ __forceinline__ float bf2f(u16 u) {
    union { unsigned int i; float f; } x;
    x.i = ((unsigned int)u) << 16;
    return x.f;
}
__device__ __forceinline__ u16 f2bf(float f) {
    union { float f; unsigned int i; } x;
    x.f = f;
    unsigned int r = x.i + 0x7fffu + ((x.i >> 16) & 1u); // round-to-nearest-even
    return (u16)(r >> 16);
}

// ---------- 0. dtype probe (resolves fp32-vs-bf16 at runtime) ----------
__global__ __launch_bounds__(256) void probe_kernel(const u16* __restrict__ w,
                                                    int* __restrict__ flag) {
    __shared__ int cnt;
    if (threadIdx.x == 0) cnt = 0;
    __syncthreads();
    int c = 0;
    for (int i = threadIdx.x; i < 4096; i += 256) {
        const u16 u = w[2 * i];
        const int e = (u >> 7) & 0xff;
        if (e >= 125) ++c;
    }
    atomicAdd(&cnt, c);
    __syncthreads();
    if (threadIdx.x == 0) *flag = (cnt > 64) ? 1 : 0;
}

// ---------- 1. embedding + positional -> bf16 h ----------
__global__ __launch_bounds__(256) void embed_kernel(const int* __restrict__ x,
                                                    const void* __restrict__ ew,
                                                    const void* __restrict__ pos,
                                                    u16* __restrict__ h,
                                                    const int* __restrict__ flagp) {
    const int f = *flagp;
    const int i = blockIdx.x;        // token row 0..MM-1
    const int t = i & (TT - 1);      // position within sequence
    const int row = x[i];
    const int c = threadIdx.x * 4;
    float4 e, p;
    if (f) {
        e = *(const float4*)((const float*)ew + (size_t)row * CC + c);
        p = *(const float4*)((const float*)pos + (size_t)t * CC + c);
    } else {
        ushort4 eu = *(const ushort4*)((const u16*)ew + (size_t)row * CC + c);
        ushort4 pu = *(const ushort4*)((const u16*)pos + (size_t)t * CC + c);
        e = make_float4(bf2f(eu.x), bf2f(eu.y), bf2f(eu.z), bf2f(eu.w));
        p = make_float4(bf2f(pu.x), bf2f(pu.y), bf2f(pu.z), bf2f(pu.w));
    }
    ushort4 o;
    o.x = f2bf(e.x + p.x); o.y = f2bf(e.y + p.y);
    o.z = f2bf(e.z + p.z); o.w = f2bf(e.w + p.w);
    *(ushort4*)&h[(size_t)i * CC + c] = o;
}

// ---------- 1b. weight convert: fp32 -> bf16 (or bf16 copy) ----------
// onlyF=1: write only when flag==1 (dst scratch exists only in fp32 mode).
__global__ __launch_bounds__(256) void cvt_w(const void* __restrict__ src,
                                             u16* __restrict__ dst,
                                             int onlyF,
                                             const int* __restrict__ flagp) {
    const int f = *flagp;
    const size_t i = ((size_t)blockIdx.x * 256 + threadIdx.x) * 8;
    if (f) {
        const float* s = (const float*)src + i;
        float4 a = *(const float4*)s;
        float4 b = *(const float4*)(s + 4);
        uint4 o;
        o.x = (unsigned)f2bf(a.x) | ((unsigned)f2bf(a.y) << 16);
        o.y = (unsigned)f2bf(a.z) | ((unsigned)f2bf(a.w) << 16);
        o.z = (unsigned)f2bf(b.x) | ((unsigned)f2bf(b.y) << 16);
        o.w = (unsigned)f2bf(b.z) | ((unsigned)f2bf(b.w) << 16);
        *(uint4*)(dst + i) = o;
    } else if (!onlyF) {
        *(uint4*)(dst + i) = *(const uint4*)((const u16*)src + i);
    }
}

// ---------- 2. MFMA GEMM: out[m,n] = sum_k A[m,k]*W[n,k] (+bias[n]) (+res[m,n]) ----------
// A bf16 [M,K]; Wc bf16 [N,K] (converted scratch). If Walt!=null and flag==0,
// W = Walt (native bf16 weights, no scratch copy in bf16 mode).
// 128x128 tile, BK=64, 256 threads = 4 waves, each wave a 64x64 sub-tile
// (4x4 f32x4 accumulators). LDS rows are 128B (64 bf16); octet o (16B) of row
// r stored at slot o^(r&7) -> every ds_read_b128/ds_write_b128 spreads 8
// lanes over each of the 8 slot-columns = all 32 banks balanced (BW floor).
// MFMA layouts (validated by flash_attn): A row=lane&15,k=(lane>>4)*8+j;
// B col=lane&15 (same); C col=lane&15, row=(lane>>4)*4+reg.
__global__ __launch_bounds__(256) void gemm_bf16(const u16* __restrict__ A,
                                                 const u16* __restrict__ Wc,
                                                 const void* __restrict__ Walt,
                                                 void* __restrict__ outP,
                                                 const void* __restrict__ bias, size_t bOff,
                                                 const u16* __restrict__ res,
                                                 int M, int N, int K, int outFlagged,
                                                 const int* __restrict__ flagp) {
    const int f = *flagp;
    const u16* W = (Walt && !f) ? (const u16*)Walt : Wc;

    __shared__ u16 As[128 * 64];   // 16 KB, swizzled
    __shared__ u16 Bs[128 * 64];   // 16 KB, swizzled
    char* AsB = (char*)As;
    char* BsB = (char*)Bs;

    const int tid = threadIdx.x;
    const int w = tid >> 6, lane = tid & 63, l15 = lane & 15, l4 = lane >> 4;
    const int m0 = blockIdx.y * 128, n0 = blockIdx.x * 128;
    const int wr = (w >> 1) * 64, wc = (w & 1) * 64;   // wave sub-tile origin

    // staging: thread -> row sr (0..127), octet group og = (tid&1)*4 .. +3
    const int sr = tid >> 1;
    const int og = (tid & 1) * 4;
    const size_t aRow = (size_t)(m0 + sr) * K + og * 8;
    const size_t wRow = (size_t)(n0 + sr) * K + og * 8;
    int dOff[4];
#pragma unroll
    for (int j = 0; j < 4; ++j)
        dOff[j] = sr * 128 + (((og + j) ^ (sr & 7)) << 4);

    f32x4 acc[4][4] = {};

    // prologue: load tile kt=0 into regs
    uint4 aR[4], wR[4];
#pragma unroll
    for (int j = 0; j < 4; ++j) {
        aR[j] = *(const uint4*)(A + aRow + j * 8);
        wR[j] = *(const uint4*)(W + wRow + j * 8);
    }

    for (int kt = 0; kt < K; kt += 64) {
        __syncthreads();            // previous tile fully consumed
#pragma unroll
        for (int j = 0; j < 4; ++j) *(uint4*)(AsB + dOff[j]) = aR[j];
#pragma unroll
        for (int j = 0; j < 4; ++j) *(uint4*)(BsB + dOff[j]) = wR[j];
        __syncthreads();
        if (kt + 64 < K) {          // issue next-tile loads; hide under MFMA
#pragma unroll
            for (int j = 0; j < 4; ++j) {
                aR[j] = *(const uint4*)(A + aRow + kt + 64 + j * 8);
                wR[j] = *(const uint4*)(W + wRow + kt + 64 + j * 8);
            }
        }
#pragma unroll
        for (int ks = 0; ks < 2; ++ks) {
            bf16x8 af[4], bfr[4];
#pragma unroll
            for (int i = 0; i < 4; ++i) {
                const int ra = wr + i * 16 + l15;
                af[i] = *(const bf16x8*)(AsB + ra * 128 + ((((ks << 2) + l4) ^ (ra & 7)) << 4));
                const int rb = wc + i * 16 + l15;
                bfr[i] = *(const bf16x8*)(BsB + rb * 128 + ((((ks << 2) + l4) ^ (rb & 7)) << 4));
            }
#pragma unroll
            for (int i = 0; i < 4; ++i)
#pragma unroll
                for (int j = 0; j < 4; ++j)
                    acc[i][j] = __builtin_amdgcn_mfma_f32_16x16x32_bf16(af[i], bfr[j], acc[i][j], 0, 0, 0);
        }
    }

    // ---- epilogue: bias + residual + store (C layout) ----
    float bv[4] = {0.f, 0.f, 0.f, 0.f};
    if (bias) {
#pragma unroll
        for (int j = 0; j < 4; ++j) {
            const int n = n0 + wc + j * 16 + l15;
            bv[j] = f ? ((const float*)bias)[bOff + n] : bf2f(((const u16*)bias)[bOff + n]);
        }
    }
#pragma unroll
    for (int i = 0; i < 4; ++i) {
#pragma unroll
        for (int r = 0; r < 4; ++r) {
            const int m = m0 + wr + i * 16 + l4 * 4 + r;
#pragma unroll
            for (int j = 0; j < 4; ++j) {
                const int n = n0 + wc + j * 16 + l15;
                float v = acc[i][j][r] + bv[j];
                if (res) v += bf2f(res[(size_t)m * N + n]);
                if (outFlagged && f) ((float*)outP)[(size_t)m * N + n] = v;
                else                 ((u16*)outP)[(size_t)m * N + n] = f2bf(v);
            }
        }
    }
}

// ---------- 3. MFMA flash attention (unchanged from R5) ----------
__global__ __launch_bounds__(256) void flash_attn(const u16* __restrict__ q,
                                                  const u16* __restrict__ k,
                                                  const u16* __restrict__ v,
                                                  u16* __restrict__ ctx) {
    const int bh = blockIdx.x;          // 0..B*H-1
    const int b = bh >> 4;              // /HH
    const int hd = bh & 15;             // %HH
    const int qt = gridDim.y - 1 - blockIdx.y;  // heavy tiles first
    const int qb = qt * 64;
    const int tid = threadIdx.x;
    const int w = tid >> 6;             // wave 0..3
    const int lane = tid & 63;
    const int l15 = lane & 15;
    const int l4 = lane >> 4;           // 0..3
    const int qw = qb + w * 16;         // wave's first query row
    const float scale = 0.125f;         // 1/sqrt(64)

    __shared__ u16 KsS[32 * 64];        // 4KB
    __shared__ u16 VtS[64 * 32];        // 4KB (transposed V)
    __shared__ u16 PwS[4][16 * 32];     // 4KB (per-wave P)
    char* Ks = (char*)KsS;
    char* Vt = (char*)VtS;
    char* Pw = (char*)PwS[w];

    // Q fragments (A operand), held in registers for the whole block
    const size_t qoff = ((size_t)(b * TT + qw + l15)) * CC + hd * DD + l4 * 8;
    const bf16x8 qf0 = *(const bf16x8*)(q + qoff);        // d 0..31 chunk
    const bf16x8 qf1 = *(const bf16x8*)(q + qoff + 32);   // d 32..63 chunk

    f32x4 zero4 = {0.f, 0.f, 0.f, 0.f};
    f32x4 ctxa[4] = {zero4, zero4, zero4, zero4};         // ctx[16 q][64 d]
    float m[4]    = {-1e30f, -1e30f, -1e30f, -1e30f};     // running row max
    float lsum[4] = {0.f, 0.f, 0.f, 0.f};                 // per-lane partial denom

    // block-cooperative staging assignment: thread -> (key row, d-octet)
    const int skey = tid >> 3;          // 0..31
    const int sd8 = tid & 7;            // 0..7
    const int kWByte = skey * 128 + ((sd8 ^ (skey & 7)) << 4);      // swizzled K dest
    const int keyx2 = (skey ^ ((sd8 & 3) << 3)) * 2;                // swizzled Vt key

    const int nt = qt * 2 + 2;          // 32-key tiles covering [0, qb+64)

    uint4 kreg, vreg;                   // register double-buffer for staging
    {
        const size_t g = ((size_t)(b * TT + skey)) * CC + hd * DD + sd8 * 8;
        kreg = *(const uint4*)(k + g);
        vreg = *(const uint4*)(v + g);
    }

    for (int t = 0; t < nt; ++t) {
        const int kv0 = t * 32;
        // ---- write staged regs -> LDS ----
        *(uint4*)(Ks + kWByte) = kreg;
        {
            const u16* vr = (const u16*)&vreg;
#pragma unroll
            for (int j = 0; j < 8; ++j)     // Vt[d][key'] transpose-scatter
                *(u16*)(Vt + (sd8 * 8 + j) * 64 + keyx2) = vr[j];
        }
        __syncthreads();
        // ---- issue next tile's global loads (latency hides under compute) ----
        if (t + 1 < nt) {
            const size_t g = ((size_t)(b * TT + kv0 + 32 + skey)) * CC + hd * DD + sd8 * 8;
            kreg = *(const uint4*)(k + g);
            vreg = *(const uint4*)(v + g);
        }
        if (kv0 <= qw + 15) {   // wave-uniform: skip fully-masked tiles
            // ---- QK^T: S[16 q][32 key], 2 C-tiles x 2 K-chunks ----
            f32x4 s[2];
#pragma unroll
            for (int c = 0; c < 2; ++c) {
                const int key = c * 16 + l15;
                const int kb = key * 128;
                const int kx = key & 7;
                const bf16x8 kf0 = *(const bf16x8*)(Ks + kb + ((l4 ^ kx) << 4));
                const bf16x8 kf1 = *(const bf16x8*)(Ks + kb + (((4 + l4) ^ kx) << 4));
                f32x4 z = {0.f, 0.f, 0.f, 0.f};
                z = __builtin_amdgcn_mfma_f32_16x16x32_bf16(qf0, kf0, z, 0, 0, 0);
                z = __builtin_amdgcn_mfma_f32_16x16x32_bf16(qf1, kf1, z, 0, 0, 0);
                s[c] = z;
            }
            // ---- scale + causal mask (element: key <= row) ----
            float sv[2][4];
#pragma unroll
            for (int c = 0; c < 2; ++c) {
                const int key = kv0 + c * 16 + l15;
#pragma unroll
                for (int r = 0; r < 4; ++r) {
                    const int row = qw + l4 * 4 + r;
                    sv[c][r] = (key <= row) ? s[c][r] * scale : -1e30f;
                }
            }
            // ---- online softmax (row spread over 16 lanes; xor 1/2/4/8 stays in group) ----
#pragma unroll
            for (int r = 0; r < 4; ++r) {
                float mt = fmaxf(sv[0][r], sv[1][r]);
                mt = fmaxf(mt, __shfl_xor(mt, 1, 64));
                mt = fmaxf(mt, __shfl_xor(mt, 2, 64));
                mt = fmaxf(mt, __shfl_xor(mt, 4, 64));
                mt = fmaxf(mt, __shfl_xor(mt, 8, 64));
                const float mn = fmaxf(m[r], mt);
                const float corr = __expf(m[r] - mn);   // 0 on first tile (m=-1e30)
                m[r] = mn;
                const float p0 = __expf(sv[0][r] - mn); // masked -> exp(-1e30)=0
                const float p1 = __expf(sv[1][r] - mn);
                lsum[r] = lsum[r] * corr + p0 + p1;
#pragma unroll
                for (int nb = 0; nb < 4; ++nb) ctxa[nb][r] *= corr;
                const int rowb = (l4 * 4 + r) * 64;
                *(u16*)(Pw + rowb + l15 * 2) = f2bf(p0);
                *(u16*)(Pw + rowb + 32 + l15 * 2) = f2bf(p1);
            }
            // ---- PV: ctx += P[16x32] * V[32x64] ----
            const bf16x8 pf = *(const bf16x8*)(Pw + l15 * 64 + l4 * 16);  // A-frag
#pragma unroll
            for (int nb = 0; nb < 4; ++nb) {
                const int d = nb * 16 + l15;
                const bf16x8 vf = *(const bf16x8*)(Vt + d * 64 + ((l4 ^ ((d >> 3) & 3)) << 4));
                ctxa[nb] = __builtin_amdgcn_mfma_f32_16x16x32_bf16(pf, vf, ctxa[nb], 0, 0, 0);
            }
        }
        __syncthreads();
    }

    // ---- epilogue: reduce denominators across the 16 column lanes, write bf16 ----
    float inv[4];
#pragma unroll
    for (int r = 0; r < 4; ++r) {
        float sred = lsum[r];
        sred += __shfl_xor(sred, 1, 64);
        sred += __shfl_xor(sred, 2, 64);
        sred += __shfl_xor(sred, 4, 64);
        sred += __shfl_xor(sred, 8, 64);
        inv[r] = 1.0f / sred;   // >0: key 0 is always unmasked in tile 0
    }
    u16* cp = ctx + ((size_t)(b * TT + qw)) * CC + hd * DD;
#pragma unroll
    for (int r = 0; r < 4; ++r) {
        const size_t rb = (size_t)(l4 * 4 + r) * CC;
#pragma unroll
        for (int nb = 0; nb < 4; ++nb)
            cp[rb + nb * 16 + l15] = f2bf(ctxa[nb][r] * inv[r]);
    }
}

// ---------- 4. d2d copy (h -> scratch), 16B per thread ----------
__global__ __launch_bounds__(256) void copy16_kernel(const uint4* __restrict__ src,
                                                     uint4* __restrict__ dst) {
    const size_t i = (size_t)blockIdx.x * 256 + threadIdx.x;
    dst[i] = src[i];
}

// ---------- 5. loss: per-row logsumexp + NLL ----------
__global__ __launch_bounds__(256) void loss_row(const void* __restrict__ logits,
                                                const int* __restrict__ target,
                                                float* __restrict__ nll,
                                                const int* __restrict__ flagp) {
    const int f = *flagp;
    const int r = blockIdx.x;
    __shared__ float red[4];
    const float* lpf = (const float*)logits + (size_t)r * VV;
    const u16*   lpb = (const u16*)logits + (size_t)r * VV;

    float lmax = -1e30f;
    if (f) { for (int i = threadIdx.x; i < VV; i += 256) lmax = fmaxf(lmax, lpf[i]); }
    else   { for (int i = threadIdx.x; i < VV; i += 256) lmax = fmaxf(lmax, bf2f(lpb[i])); }
#pragma unroll
    for (int off = 32; off > 0; off >>= 1) lmax = fmaxf(lmax, __shfl_down(lmax, off, 64));
    const int wid = threadIdx.x >> 6, lid = threadIdx.x & 63;
    if (lid == 0) red[wid] = lmax;
    __syncthreads();
    lmax = fmaxf(fmaxf(red[0], red[1]), fmaxf(red[2], red[3]));

    float sum = 0.f;
    if (f) { for (int i = threadIdx.x; i < VV; i += 256) sum += __expf(lpf[i] - lmax); }
    else   { for (int i = threadIdx.x; i < VV; i += 256) sum += __expf(bf2f(lpb[i]) - lmax); }
#pragma unroll
    for (int off = 32; off > 0; off >>= 1) sum += __shfl_down(sum, off, 64);
    __syncthreads();
    if (lid == 0) red[wid] = sum;
    __syncthreads();
    if (threadIdx.x == 0) {
        const float s = red[0] + red[1] + red[2] + red[3];
        const float tl = f ? lpf[target[r]] : bf2f(lpb[target[r]]);
        nll[r] = lmax + __logf(s) - tl;   // = -(log_softmax at target)
    }
}

__global__ __launch_bounds__(256) void loss_final(const float* __restrict__ nll,
                                                  void* __restrict__ out,
                                                  const int* __restrict__ flagp) {
    __shared__ float red[4];
    float s = 0.f;
    for (int i = threadIdx.x; i < MM; i += 256) s += nll[i];
#pragma unroll
    for (int off = 32; off > 0; off >>= 1) s += __shfl_down(s, off, 64);
    if ((threadIdx.x & 63) == 0) red[threadIdx.x >> 6] = s;
    __syncthreads();
    if (threadIdx.x == 0) {
        const float t = (red[0] + red[1] + red[2] + red[3]) / (float)MM;
        if (*flagp) ((float*)out)[(size_t)MM * VV] = t;
        else        ((u16*)out)[(size_t)MM * VV] = f2bf(t);
    }
}

// ---------- launch ----------
extern "C" void kernel_launch(void* const* d_in, const int* in_sizes, int n_in,
                              void* d_out, int out_size, void* d_ws, size_t ws_size,
                              hipStream_t stream) {
    const int* x      = (const int*)d_in[0];
    const int* target = (const int*)d_in[1];
    const void* ew  = d_in[2];
    const void* pos = d_in[3];
    const void* Wq  = d_in[4];
    const void* bq  = d_in[5];
    const void* Wk  = d_in[6];
    const void* bk  = d_in[7];
    const void* Wv  = d_in[8];
    const void* bv  = d_in[9];
    const void* Wo  = d_in[10];
    const void* bo  = d_in[11];
    const void* Wu  = d_in[12];

    int* flagp = (int*)d_ws;   // 4 bytes of workspace: dtype flag

    // bf16 scratch inside d_out (dead until logits GEMM; >=64 MiB both modes):
    u16* outw = (u16*)d_out;
    u16* hB  = outw;                                  // [ 0M,  8M)
    u16* qB  = outw + (size_t)1 * MM * CC;            // [ 8M, 16M)
    u16* kB  = outw + (size_t)2 * MM * CC;            // [16M, 24M)
    u16* vB  = outw + (size_t)3 * MM * CC;            // [24M, 32M)
    u16* ctx = qB;  // flash block writes exactly the (row, head-slice) it read
    // bf16 projection weights in d_out [32M, 48M) (both modes; dead until
    // the logits GEMM, and all consumers run before it):
    const size_t WSZ = (size_t)LL * CC * CC;          // 2M elements = 4MB bf16
    u16* WqB = (u16*)((char*)d_out + (size_t)32 * 1024 * 1024);
    u16* WkB = WqB + WSZ;
    u16* WvB = WkB + WSZ;
    u16* WoB = WvB + WSZ;
    // Scratch inside the consumed embed_w buffer (fp32 mode: 32 MiB; bf16: 16 MiB):
    u16* hScr  = (u16*)ew;                                   // [ 0M,  8M)
    float* nll = (float*)((char*)ew + 12u * 1024 * 1024);    // [12M, 12M+16K)
    u16* WuB   = (u16*)((char*)ew + 16u * 1024 * 1024);      // [16M, 32M) fp32 mode ONLY

    probe_kernel<<<1, 256, 0, stream>>>((const u16*)Wu, flagp);
    embed_kernel<<<MM, 256, 0, stream>>>(x, ew, pos, hB, flagp);  // last read of ew table

    // weight conversion (after embed: WuB overlays the live embedding table)
    cvt_w<<<WSZ / 2048, 256, 0, stream>>>(Wq, WqB, 0, flagp);
    cvt_w<<<WSZ / 2048, 256, 0, stream>>>(Wk, WkB, 0, flagp);
    cvt_w<<<WSZ / 2048, 256, 0, stream>>>(Wv, WvB, 0, flagp);
    cvt_w<<<WSZ / 2048, 256, 0, stream>>>(Wo, WoB, 0, flagp);
    cvt_w<<<(size_t)VV * CC / 2048, 256, 0, stream>>>(Wu, WuB, 1, flagp);  // fp32 mode only

    const dim3 gP(CC / 128, MM / 128);   // projection GEMMs: 8 x 32 blocks
    for (int l = 0; l < LL; ++l) {
        const size_t wOffE = (size_t)l * CC * CC, bOff = (size_t)l * CC;
        gemm_bf16<<<gP, 256, 0, stream>>>(hB, WqB + wOffE, nullptr, qB, bq, bOff, nullptr, MM, CC, CC, 0, flagp);
        gemm_bf16<<<gP, 256, 0, stream>>>(hB, WkB + wOffE, nullptr, kB, bk, bOff, nullptr, MM, CC, CC, 0, flagp);
        gemm_bf16<<<gP, 256, 0, stream>>>(hB, WvB + wOffE, nullptr, vB, bv, bOff, nullptr, MM, CC, CC, 0, flagp);
        flash_attn<<<dim3(BB * HH, TT / 64), 256, 0, stream>>>(qB, kB, vB, ctx);
        // out-proj + residual, in-place into hB (res read/write at identical (m,n))
        gemm_bf16<<<gP, 256, 0, stream>>>(ctx, WoB + wOffE, nullptr, hB, bo, bOff, hB, MM, CC, CC, 0, flagp);
    }

    // move h out of d_out, then logits GEMM overwrites d_out (dtype per flag)
    copy16_kernel<<<(MM * CC * 2 / 16) / 256, 256, 0, stream>>>((const uint4*)hB, (uint4*)hScr);
    gemm_bf16<<<dim3(VV / 128, MM / 128), 256, 0, stream>>>(hScr, WuB, Wu, d_out,
                                                            nullptr, 0, nullptr, MM, VV, CC, 1, flagp);
    loss_row<<<MM, 256, 0, stream>>>(d_out, target, nll, flagp);
    loss_final<<<1, 256, 0, stream>>>(nll, d_out, flagp);
}